// Round 2
// baseline (60.845 us; speedup 1.0000x reference)
//
#include <hip/hip_runtime.h>

// SITH: out[t,o,f] = subset[o] * sum_n invL_sub[o,n] * ts[t,n,f]
//   ts[t,n,f] = d[n]*ts[t-1,n,f] + decay[n]*inp[t,f]
// invL_sub is banded: row o nonzero only for n in [4o, 4o+8] (D tridiag -> D^4
// band halfwidth 4). We use guarded 11-tap window n in [4o-1, 4o+9].

#define SEQL 512
#define NF   512    // features
#define NN   408    // n (tau) dimension
#define NO   100    // output rows
#define NC   16     // time chunks
#define TC   32     // steps per chunk (SEQL/NC)
#define FS   16     // features per pass-2 block
#define TAPS 11
#define ROWS 35     // state rows per thread: [28g-1, 28g+33]
#define OPG  7      // outputs per o-group (ceil(100/15))

// ---------------- Pass 1: chunk-boundary states ----------------
// thread = one (n,f); runs full 512-step scan, stores state at chunk ends.
__global__ __launch_bounds__(256) void sith_pass1(
    const float* __restrict__ inp, const float* __restrict__ d,
    const float* __restrict__ decay, float* __restrict__ S)
{
    int gid = blockIdx.x * 256 + threadIdx.x;
    if (gid >= NN * NF) return;
    int n = gid >> 9;          // /512
    int f = gid & (NF - 1);
    float dn = d[n];
    float gn = decay[n];
    float st = 0.f;
    const float* ip = inp + f;
    for (int b = 0; b < NC; ++b) {
        #pragma unroll
        for (int tt = 0; tt < TC; ++tt) {
            float x = ip[(size_t)(b * TC + tt) * NF];
            st = fmaf(dn, st, gn * x);
        }
        if (b < NC - 1) S[(size_t)b * (NN * NF) + gid] = st;
    }
}

// ---------------- Pass 2: per-chunk scan + banded projection ----------------
// block = (chunk c, f-slice of 16). 256 threads = 16 fl x 16 o-groups.
// Each thread keeps 35 state rows + constants in registers (all indices
// compile-time via full unroll -> no scratch).
__global__ __launch_bounds__(256) void sith_pass2(
    const float* __restrict__ inp, const float* __restrict__ invL,
    const float* __restrict__ d, const float* __restrict__ decay,
    const float* __restrict__ subset, const float* __restrict__ S,
    float* __restrict__ out)
{
    int bid = blockIdx.x;
    int c  = bid >> 5;              // chunk 0..15
    int fs = bid & 31;              // f-slice
    int f0 = fs * FS;
    int tid = threadIdx.x;
    int fl = tid & (FS - 1);
    int g  = tid >> 4;              // o-group 0..15
    int f  = f0 + fl;
    int nbase = 28 * g - 1;         // row j -> n = nbase + j

    float dreg[ROWS], greg[ROWS], st[ROWS];
    #pragma unroll
    for (int j = 0; j < ROWS; ++j) {
        int n = nbase + j;
        bool v = (n >= 0) && (n < NN);
        int ncl = v ? n : 0;
        dreg[j] = v ? d[ncl] : 0.f;
        greg[j] = v ? decay[ncl] : 0.f;
        if (c == 0) st[j] = 0.f;
        else        st[j] = v ? S[(size_t)(c - 1) * (NN * NF) + (size_t)ncl * NF + f] : 0.f;
    }

    float L[OPG][TAPS];
    #pragma unroll
    for (int k = 0; k < OPG; ++k) {
        int o = 7 * g + k;
        bool ov = (o < NO);
        float sub = ov ? subset[o] : 0.f;
        #pragma unroll
        for (int dd = 0; dd < TAPS; ++dd) {
            int n = nbase + 4 * k + dd;   // = 4o - 1 + dd
            bool v = ov && (n >= 0) && (n < NN);
            L[k][dd] = v ? invL[(size_t)o * NN + n] * sub : 0.f;
        }
    }

    const float* ip = inp + f;
    int t0 = c * TC;
    size_t obase = (size_t)t0 * NO * NF + (size_t)(7 * g) * NF + f;

#define SITH_STEP(xv)                                                      \
    {                                                                      \
        _Pragma("unroll")                                                  \
        for (int j = 0; j < ROWS; ++j)                                     \
            st[j] = fmaf(dreg[j], st[j], greg[j] * (xv));                  \
        _Pragma("unroll")                                                  \
        for (int k = 0; k < OPG; ++k) {                                    \
            if (7 * g + k < NO) {                                          \
                float acc = 0.f;                                           \
                _Pragma("unroll")                                          \
                for (int dd = 0; dd < TAPS; ++dd)                          \
                    acc = fmaf(L[k][dd], st[4 * k + dd], acc);             \
                out[obase + (size_t)k * NF] = acc;                         \
            }                                                              \
        }                                                                  \
        obase += (size_t)NO * NF;                                          \
    }

    // unroll-by-4 over time: 4 independent x loads issue together, then
    // 4 recurrence+projection stages (dep chain is only the 35 st regs).
    for (int tq = 0; tq < TC; tq += 4) {
        float x0 = ip[(size_t)(t0 + tq + 0) * NF];
        float x1 = ip[(size_t)(t0 + tq + 1) * NF];
        float x2 = ip[(size_t)(t0 + tq + 2) * NF];
        float x3 = ip[(size_t)(t0 + tq + 3) * NF];
        SITH_STEP(x0);
        SITH_STEP(x1);
        SITH_STEP(x2);
        SITH_STEP(x3);
    }
#undef SITH_STEP
}

extern "C" void kernel_launch(void* const* d_in, const int* in_sizes, int n_in,
                              void* d_out, int out_size, void* d_ws, size_t ws_size,
                              hipStream_t stream)
{
    const float* inp    = (const float*)d_in[0];
    const float* invL   = (const float*)d_in[1];
    const float* d      = (const float*)d_in[2];
    const float* decay  = (const float*)d_in[3];
    const float* subset = (const float*)d_in[4];
    float* out = (float*)d_out;
    float* S   = (float*)d_ws;   // 15 * 408 * 512 * 4 B = 12.5 MB boundary states

    sith_pass1<<<(NN * NF + 255) / 256, 256, 0, stream>>>(inp, d, decay, S);
    sith_pass2<<<NC * (NF / FS), 256, 0, stream>>>(inp, invL, d, decay, subset, S, out);
}

// Round 3
// 55.584 us; speedup vs baseline: 1.0946x; 1.0946x over previous
//
#include <hip/hip_runtime.h>

// SITH: out[t,o,f] = subset[o] * sum_n invL_sub[o,n] * ts[t,n,f]
//   ts[t,n,f] = d[n]*ts[t-1,n,f] + decay[n]*inp[t,f]
// invL_sub row o is exactly banded: nonzero only n in [4o, 4o+8].
// Guarded 11-tap window n in [4o-1, 4o+9].
//
// R3 change vs R2: pass-2 lane map is now lane=f (64 consecutive features per
// wave), wave=o-group. Every out-store is one 256-B contiguous wave
// transaction (was 4x64-B segments). Nontemporal stores, 32-bit offsets.

#define SEQL 512
#define NF   512
#define NN   408
#define NO   100
#define NC   16     // time chunks
#define TC   32     // steps per chunk
#define TAPS 11
#define ROWS 35     // state rows per o-group window [28g-1, 28g+33]
#define OPG  7      // outputs per o-group

// ---------------- Pass 1: chunk-boundary states ----------------
__global__ __launch_bounds__(256) void sith_pass1(
    const float* __restrict__ inp, const float* __restrict__ d,
    const float* __restrict__ decay, float* __restrict__ S)
{
    int gid = blockIdx.x * 256 + threadIdx.x;
    if (gid >= NN * NF) return;
    int n = gid >> 9;
    int f = gid & (NF - 1);
    float dn = d[n];
    float gn = decay[n];
    float st = 0.f;
    const float* ip = inp + f;
    for (int b = 0; b < NC; ++b) {
        #pragma unroll
        for (int tt = 0; tt < TC; ++tt) {
            float x = ip[(b * TC + tt) * NF];
            st = fmaf(dn, st, gn * x);
        }
        if (b < NC - 1) S[b * (NN * NF) + gid] = st;
    }
}

// ---------------- Pass 2: per-chunk scan + banded projection ----------------
// block = (chunk c, o-chunk oc, f-slice fs). 256 threads = 4 waves.
// lane = f (64 consecutive), wave w -> o-group g = 4*oc + w (7 outputs).
// Per thread: 35 state rows + 35 d + 35 decay + 77 L taps in registers,
// all compile-time indexed (full unroll) -> no LDS, no scratch.
__global__ __launch_bounds__(256) void sith_pass2(
    const float* __restrict__ inp, const float* __restrict__ invL,
    const float* __restrict__ d, const float* __restrict__ decay,
    const float* __restrict__ subset, const float* __restrict__ S,
    float* __restrict__ out)
{
    int bid = blockIdx.x;
    int fs = bid & 7;              // f-slice 0..7
    int oc = (bid >> 3) & 3;       // o-chunk 0..3
    int c  = bid >> 5;             // time chunk 0..15
    int tid = threadIdx.x;
    int lane = tid & 63;
    int w = tid >> 6;              // wave 0..3
    int g = oc * 4 + w;            // o-group 0..15
    int f = fs * 64 + lane;
    int nbase = 28 * g - 1;        // row j -> n = nbase + j

    float dreg[ROWS], greg[ROWS], st[ROWS];
    #pragma unroll
    for (int j = 0; j < ROWS; ++j) {
        int n = nbase + j;
        bool v = (n >= 0) && (n < NN);
        int ncl = v ? n : 0;
        dreg[j] = v ? d[ncl] : 0.f;
        greg[j] = v ? decay[ncl] : 0.f;
        if (c == 0) st[j] = 0.f;
        else        st[j] = v ? S[(c - 1) * (NN * NF) + ncl * NF + f] : 0.f;
    }

    float L[OPG][TAPS];
    #pragma unroll
    for (int k = 0; k < OPG; ++k) {
        int o = OPG * g + k;
        bool ov = (o < NO);
        float sub = ov ? subset[ov ? o : 0] : 0.f;
        #pragma unroll
        for (int dd = 0; dd < TAPS; ++dd) {
            int n = nbase + 4 * k + dd;   // = 4o - 1 + dd
            bool v = ov && (n >= 0) && (n < NN);
            L[k][dd] = v ? invL[o * NN + n] * sub : 0.f;
        }
    }

    const float* ip = inp + f;
    int t0 = c * TC;
    int obase = (t0 * NO + OPG * g) * NF + f;   // fits in int (max ~26.2M)

#define SITH_STEP(xv)                                                      \
    {                                                                      \
        _Pragma("unroll")                                                  \
        for (int j = 0; j < ROWS; ++j)                                     \
            st[j] = fmaf(dreg[j], st[j], greg[j] * (xv));                  \
        _Pragma("unroll")                                                  \
        for (int k = 0; k < OPG; ++k) {                                    \
            if (OPG * g + k < NO) {                                        \
                float acc = 0.f;                                           \
                _Pragma("unroll")                                          \
                for (int dd = 0; dd < TAPS; ++dd)                          \
                    acc = fmaf(L[k][dd], st[4 * k + dd], acc);             \
                __builtin_nontemporal_store(acc, &out[obase + k * NF]);    \
            }                                                              \
        }                                                                  \
        obase += NO * NF;                                                  \
    }

    for (int tq = 0; tq < TC; tq += 4) {
        float x0 = ip[(t0 + tq + 0) * NF];
        float x1 = ip[(t0 + tq + 1) * NF];
        float x2 = ip[(t0 + tq + 2) * NF];
        float x3 = ip[(t0 + tq + 3) * NF];
        SITH_STEP(x0);
        SITH_STEP(x1);
        SITH_STEP(x2);
        SITH_STEP(x3);
    }
#undef SITH_STEP
}

extern "C" void kernel_launch(void* const* d_in, const int* in_sizes, int n_in,
                              void* d_out, int out_size, void* d_ws, size_t ws_size,
                              hipStream_t stream)
{
    const float* inp    = (const float*)d_in[0];
    const float* invL   = (const float*)d_in[1];
    const float* d      = (const float*)d_in[2];
    const float* decay  = (const float*)d_in[3];
    const float* subset = (const float*)d_in[4];
    float* out = (float*)d_out;
    float* S   = (float*)d_ws;   // 15 * 408 * 512 * 4 B = 12.5 MB boundary states

    sith_pass1<<<(NN * NF + 255) / 256, 256, 0, stream>>>(inp, d, decay, S);
    sith_pass2<<<NC * 4 * 8, 256, 0, stream>>>(inp, invL, d, decay, subset, S, out);
}

// Round 4
// 53.852 us; speedup vs baseline: 1.1298x; 1.0322x over previous
//
#include <hip/hip_runtime.h>

// SITH: out[t,o,f] = subset[o] * sum_n invL_sub[o,n] * ts[t,n,f]
//   ts[t,n,f] = d[n]*ts[t-1,n,f] + decay[n]*inp[t,f]
// invL_sub row o is exactly banded: nonzero only n in [4o, 4o+8].
// Guarded 11-tap window n in [4o-1, 4o+9].
//
// R4 vs R3:
//  - pass1: 4 n-rows per thread (x load amortized 4x -> L2 traffic /4),
//    t-unrolled x8, skips the final chunk (its boundary is never stored).
//  - pass2: OPG=5, 20 o-groups (exactly 100 outputs, no wasted wave),
//    window 27 rows (was 35), taps fit window exactly, no o-bound branch.

#define SEQL 512
#define NF   512
#define NN   408
#define NO   100
#define NC   16     // time chunks
#define TC   32     // steps per chunk
#define TAPS 11
#define OPG  5      // outputs per o-group
#define NG   20     // o-groups (NG*OPG == NO exactly)
#define ROWS 27     // state rows per o-group window [20g-1, 20g+25]
#define NPT  4      // n-rows per pass1 thread

// ---------------- Pass 1: chunk-boundary states ----------------
// thread = (n-quad, f); one x load feeds 4 recurrence chains.
__global__ __launch_bounds__(256) void sith_pass1(
    const float* __restrict__ inp, const float* __restrict__ d,
    const float* __restrict__ decay, float* __restrict__ S)
{
    int gid = blockIdx.x * 256 + threadIdx.x;      // 102*512 threads
    int nq = gid >> 9;                             // n-quad 0..101
    int f  = gid & (NF - 1);
    int n0 = nq * NPT;

    float dreg[NPT], greg[NPT], st[NPT];
    #pragma unroll
    for (int q = 0; q < NPT; ++q) {
        dreg[q] = d[n0 + q];
        greg[q] = decay[n0 + q];
        st[q] = 0.f;
    }

    const float* ip = inp + f;
    for (int b = 0; b < NC - 1; ++b) {             // last chunk never stored
        #pragma unroll
        for (int tt = 0; tt < TC; tt += 8) {
            float x[8];
            #pragma unroll
            for (int u = 0; u < 8; ++u)
                x[u] = ip[(b * TC + tt + u) * NF];
            #pragma unroll
            for (int u = 0; u < 8; ++u) {
                #pragma unroll
                for (int q = 0; q < NPT; ++q)
                    st[q] = fmaf(dreg[q], st[q], greg[q] * x[u]);
            }
        }
        #pragma unroll
        for (int q = 0; q < NPT; ++q)
            S[b * (NN * NF) + (n0 + q) * NF + f] = st[q];
    }
}

// ---------------- Pass 2: per-chunk scan + banded projection ----------------
// block = (chunk c, o-chunk oc, f-slice fs). 256 threads = 4 waves.
// lane = f (64 consecutive), wave w -> o-group g = 4*oc + w (5 outputs).
// Per thread: 27 state rows + 27 d + 27 decay + 55 L taps in registers,
// all compile-time indexed (full unroll) -> no LDS, no scratch.
__global__ __launch_bounds__(256) void sith_pass2(
    const float* __restrict__ inp, const float* __restrict__ invL,
    const float* __restrict__ d, const float* __restrict__ decay,
    const float* __restrict__ subset, const float* __restrict__ S,
    float* __restrict__ out)
{
    int bid = blockIdx.x;                 // 16c * 5oc * 8fs = 640
    int fs = bid & 7;
    int r  = bid >> 3;
    int oc = r % 5;
    int c  = r / 5;
    int tid = threadIdx.x;
    int lane = tid & 63;
    int w = tid >> 6;
    int g = oc * 4 + w;                   // 0..19
    int f = fs * 64 + lane;
    int nbase = NG * g - 1;               // row j -> n = nbase + j, j in [0,27)

    float dreg[ROWS], greg[ROWS], st[ROWS];
    #pragma unroll
    for (int j = 0; j < ROWS; ++j) {
        int n = nbase + j;
        bool v = (n >= 0);                // n <= 20*19+25 = 405 < 408 always
        int ncl = v ? n : 0;
        dreg[j] = v ? d[ncl] : 0.f;
        greg[j] = v ? decay[ncl] : 0.f;
        if (c == 0) st[j] = 0.f;
        else        st[j] = v ? S[(c - 1) * (NN * NF) + ncl * NF + f] : 0.f;
    }

    float L[OPG][TAPS];
    #pragma unroll
    for (int k = 0; k < OPG; ++k) {
        int o = OPG * g + k;              // < 100 always
        float sub = subset[o];
        #pragma unroll
        for (int dd = 0; dd < TAPS; ++dd) {
            int n = nbase + 4 * k + dd;   // = 4o - 1 + dd, j = 4k+dd in [0,27)
            bool v = (n >= 0);
            L[k][dd] = v ? invL[o * NN + n] * sub : 0.f;
        }
    }

    const float* ip = inp + f;
    int t0 = c * TC;
    int obase = (t0 * NO + OPG * g) * NF + f;

#define SITH_STEP(xv)                                                      \
    {                                                                      \
        _Pragma("unroll")                                                  \
        for (int j = 0; j < ROWS; ++j)                                     \
            st[j] = fmaf(dreg[j], st[j], greg[j] * (xv));                  \
        _Pragma("unroll")                                                  \
        for (int k = 0; k < OPG; ++k) {                                    \
            float acc = 0.f;                                               \
            _Pragma("unroll")                                              \
            for (int dd = 0; dd < TAPS; ++dd)                              \
                acc = fmaf(L[k][dd], st[4 * k + dd], acc);                 \
            __builtin_nontemporal_store(acc, &out[obase + k * NF]);        \
        }                                                                  \
        obase += NO * NF;                                                  \
    }

    for (int tq = 0; tq < TC; tq += 4) {
        float x0 = ip[(t0 + tq + 0) * NF];
        float x1 = ip[(t0 + tq + 1) * NF];
        float x2 = ip[(t0 + tq + 2) * NF];
        float x3 = ip[(t0 + tq + 3) * NF];
        SITH_STEP(x0);
        SITH_STEP(x1);
        SITH_STEP(x2);
        SITH_STEP(x3);
    }
#undef SITH_STEP
}

extern "C" void kernel_launch(void* const* d_in, const int* in_sizes, int n_in,
                              void* d_out, int out_size, void* d_ws, size_t ws_size,
                              hipStream_t stream)
{
    const float* inp    = (const float*)d_in[0];
    const float* invL   = (const float*)d_in[1];
    const float* d      = (const float*)d_in[2];
    const float* decay  = (const float*)d_in[3];
    const float* subset = (const float*)d_in[4];
    float* out = (float*)d_out;
    float* S   = (float*)d_ws;   // 15 * 408 * 512 * 4 B = 12.5 MB boundary states

    sith_pass1<<<(NN / NPT) * (NF / 256), 256, 0, stream>>>(inp, d, decay, S);
    sith_pass2<<<NC * 5 * 8, 256, 0, stream>>>(inp, invL, d, decay, subset, S, out);
}